// Round 4
// baseline (5543.065 us; speedup 1.0000x reference)
//
#include <hip/hip_runtime.h>
#include <hip/hip_bf16.h>
#include <math.h>

#define V     10000
#define EMB   512
#define H     1024
#define H3    3072
#define SEQ   64
#define NPAD  10048   // 157*64, padded N for score partials

typedef __attribute__((ext_vector_type(8))) unsigned short us8;

__device__ __forceinline__ float sigmoidf_(float x) { return 1.0f / (1.0f + expf(-x)); }
__device__ __forceinline__ float bf2f(unsigned short u) { return __uint_as_float(((unsigned)u) << 16); }
__device__ __forceinline__ unsigned short f2bf_rne(float f) {
    unsigned u = __float_as_uint(f);
    unsigned r = u + 0x7FFF + ((u >> 16) & 1);
    return (unsigned short)(r >> 16);
}

// ---------------- f32 -> bf16 weight conversion ----------------
__global__ __launch_bounds__(256) void f2bf_kernel(const float* __restrict__ src,
                                                   unsigned short* __restrict__ dst, int n) {
    int i = (blockIdx.x * 256 + threadIdx.x) * 8;
    if (i >= n) return;
    float4 a = *(const float4*)(src + i);
    float4 b = *(const float4*)(src + i + 4);
    us8 o;
    o[0] = f2bf_rne(a.x); o[1] = f2bf_rne(a.y); o[2] = f2bf_rne(a.z); o[3] = f2bf_rne(a.w);
    o[4] = f2bf_rne(b.x); o[5] = f2bf_rne(b.y); o[6] = f2bf_rne(b.z); o[7] = f2bf_rne(b.w);
    *(us8*)(dst + i) = o;
}

// ---------------- init: h ping-pong buffers + barrier counters ----------------
__global__ void init_h_kernel(const float* __restrict__ enc_state,
                              float* __restrict__ h0buf, float* __restrict__ h1buf,
                              int* __restrict__ bar) {
    int i = blockIdx.x * blockDim.x + threadIdx.x;
    if (i < H)            h0buf[i] = enc_state[i];
    else if (i < 2 * H)   h1buf[H + (i - H)] = enc_state[i];
    if (i < 128) bar[i] = 0;
}

// ---------------- embedding gather ----------------
__global__ void embed_kernel(const int* __restrict__ cs, const int* __restrict__ sos,
                             const int* __restrict__ tgt, const float* __restrict__ emb,
                             float* __restrict__ e_enc, float* __restrict__ e_dec) {
    int t = blockIdx.x;  // 0..127
    int id;
    float* dst;
    if (t < SEQ) { id = cs[t]; dst = e_enc + (size_t)t * EMB; }
    else         { int td = t - SEQ; id = (td == 0) ? sos[0] : tgt[td - 1]; dst = e_dec + (size_t)td * EMB; }
    const float4* src4 = (const float4*)(emb + (size_t)id * EMB);
    float4* dst4 = (float4*)dst;
    dst4[threadIdx.x] = src4[threadIdx.x];
}

// ---------------- gi0 = e @ Wih0.T + bih0 for all 64 timesteps (f32) ----------------
__global__ __launch_bounds__(256) void gi0_kernel(const float* __restrict__ e,
                                                  const float* __restrict__ W,
                                                  const float* __restrict__ bih,
                                                  float* __restrict__ gi) {
    int wave = (blockIdx.x * 256 + threadIdx.x) >> 6;
    int lane = threadIdx.x & 63;
    if (wave >= H3) return;
    int row = wave;
    float4 w0 = *(const float4*)(W + (size_t)row * EMB + lane * 8);
    float4 w1 = *(const float4*)(W + (size_t)row * EMB + lane * 8 + 4);
    float bb = bih[row];
    for (int t = 0; t < SEQ; ++t) {
        float4 x0 = *(const float4*)(e + (size_t)t * EMB + lane * 8);
        float4 x1 = *(const float4*)(e + (size_t)t * EMB + lane * 8 + 4);
        float s = w0.x * x0.x + w0.y * x0.y + w0.z * x0.z + w0.w * x0.w
                + w1.x * x1.x + w1.y * x1.y + w1.z * x1.z + w1.w * x1.w;
        #pragma unroll
        for (int m = 1; m < 64; m <<= 1) s += __shfl_xor(s, m);
        if (lane == 0) gi[(size_t)t * H3 + row] = s + bb;
    }
}

// ================= persistent recurrence kernel =================
// 384 blocks x 512 threads (8 waves). Blocks 0..127 = A (layer0): 8 j's/block,
// wave w -> j = bid*8+w, owns all 3 gate rows. Blocks 128..383 = B (layer1):
// 4 j's/block, wave w -> j = bb*4 + (w>>1); part = w&1 (0: Wih gates, 1: Whh gates).
// Each wave holds enc+dec weight rows in VGPRs (bf16, packed 2/uint, interleaved:
// lane l owns elements k = l + 64*e). 129 phases separated by a hierarchical
// grid barrier (monotonic counters; release/acquire threadfences for XCD coherence).
struct PArgs {
    const unsigned short *encWhh0, *encWih1, *encWhh1;
    const unsigned short *decWhh0, *decWih1, *decWhh1;
    const float *gi_enc0, *gi_dec0;
    const float *enc_bhh0, *dec_bhh0;
    const float *enc_bih1, *enc_bhh1, *dec_bih1, *dec_bhh1;
    float *h0buf, *h1buf, *states;
    int *bar;   // [0]=flag, [32]=root counter, [64..111]=48 group counters
};

__global__ __launch_bounds__(512, 4) void persist_kernel(PArgs a) {
    __shared__ float xh0[H];
    __shared__ float xh1[H];
    __shared__ float sred[32];
    const int tid = threadIdx.x;
    const int w = tid >> 6, lane = tid & 63;
    const int bid = blockIdx.x;
    const bool isA = (bid < 128);
    int j, part = 0;
    if (isA) j = bid * 8 + w;
    else { int bb = bid - 128; j = bb * 4 + (w >> 1); part = w & 1; }

    // ---- one-time weight preload into VGPRs (enc + dec variants) ----
    unsigned we[3][8], wd[3][8];
    {
        const unsigned short *me, *md;
        if (isA)            { me = a.encWhh0; md = a.decWhh0; }
        else if (part == 0) { me = a.encWih1; md = a.decWih1; }
        else                { me = a.encWhh1; md = a.decWhh1; }
        #pragma unroll
        for (int g = 0; g < 3; ++g) {
            size_t base = (size_t)(g * H + j) * H + lane;
            #pragma unroll
            for (int q = 0; q < 8; ++q) {
                we[g][q] = (unsigned)me[base + 128 * q] | ((unsigned)me[base + 128 * q + 64] << 16);
                wd[g][q] = (unsigned)md[base + 128 * q] | ((unsigned)md[base + 128 * q + 64] << 16);
            }
        }
    }

    for (int p = 0; p <= 128; ++p) {
        // stage current h vectors into LDS
        const float* h0r = a.h0buf + (p & 1) * H;
        const float* h1r = a.h1buf + (p & 1) * H;
        if (tid < 256) *(float4*)(xh0 + tid * 4)         = *(const float4*)(h0r + tid * 4);
        else           *(float4*)(xh1 + (tid - 256) * 4) = *(const float4*)(h1r + (tid - 256) * 4);
        __syncthreads();

        const bool hasA = (p <= 127), hasB = (p >= 1);
        const bool active = isA ? hasA : hasB;
        float s0 = 0.f, s1 = 0.f, s2 = 0.f;
        if (active) {
            const float* x = (isA || part == 0) ? xh0 : xh1;
            const bool useenc = isA ? (p < 64) : (p <= 64);
            auto dot3 = [&](const unsigned (&wr)[3][8]) {
                #pragma unroll
                for (int q = 0; q < 8; ++q) {
                    float x0 = x[lane + 128 * q];
                    float x1 = x[lane + 128 * q + 64];
                    s0 += __uint_as_float(wr[0][q] << 16) * x0 + __uint_as_float(wr[0][q] & 0xffff0000u) * x1;
                    s1 += __uint_as_float(wr[1][q] << 16) * x0 + __uint_as_float(wr[1][q] & 0xffff0000u) * x1;
                    s2 += __uint_as_float(wr[2][q] << 16) * x0 + __uint_as_float(wr[2][q] & 0xffff0000u) * x1;
                }
            };
            if (useenc) dot3(we); else dot3(wd);
            #pragma unroll
            for (int m = 1; m < 64; m <<= 1) {
                s0 += __shfl_xor(s0, m);
                s1 += __shfl_xor(s1, m);
                s2 += __shfl_xor(s2, m);
            }
            if (isA) {
                if (lane == 0) {
                    const float* gi  = (p < 64) ? (a.gi_enc0 + (size_t)p * H3)
                                                : (a.gi_dec0 + (size_t)(p - 64) * H3);
                    const float* bhh = (p < 64) ? a.enc_bhh0 : a.dec_bhh0;
                    float r = sigmoidf_(gi[j] + s0 + bhh[j]);
                    float z = sigmoidf_(gi[H + j] + s1 + bhh[H + j]);
                    float n = tanhf(gi[2 * H + j] + r * (s2 + bhh[2 * H + j]));
                    float hn = (1.f - z) * n + z * xh0[j];
                    a.h0buf[((p + 1) & 1) * H + j] = hn;
                    if (p >= 64) a.states[(size_t)(p - 64) * 2048 + j] = hn;
                }
            } else if (lane == 0) {
                int slot = (w >> 1) * 8 + part * 4;
                sred[slot + 0] = s0; sred[slot + 1] = s1; sred[slot + 2] = s2;
            }
        }
        __syncthreads();
        if (!isA && hasB && tid < 4) {
            int jg = (bid - 128) * 4 + tid;
            const float* bih = (p <= 64) ? a.enc_bih1 : a.dec_bih1;
            const float* bhh = (p <= 64) ? a.enc_bhh1 : a.dec_bhh1;
            float si0 = sred[tid * 8 + 0], si1 = sred[tid * 8 + 1], si2 = sred[tid * 8 + 2];
            float sh0 = sred[tid * 8 + 4], sh1 = sred[tid * 8 + 5], sh2 = sred[tid * 8 + 6];
            float r = sigmoidf_(si0 + bih[jg] + sh0 + bhh[jg]);
            float z = sigmoidf_(si1 + bih[H + jg] + sh1 + bhh[H + jg]);
            float n = tanhf(si2 + bih[2 * H + jg] + r * (sh2 + bhh[2 * H + jg]));
            float hn = (1.f - z) * n + z * xh1[jg];
            a.h1buf[((p + 1) & 1) * H + jg] = hn;
            if (p >= 65) a.states[(size_t)(p - 65) * 2048 + H + jg] = hn;
        }
        if (p < 128) {
            // ---- grid barrier (hierarchical, monotonic counters) ----
            __syncthreads();
            if (tid == 0) {
                __threadfence();   // release: drain + write back L2 (cross-XCD visibility)
                int* gc = a.bar + 64 + (bid >> 3);
                if ((__hip_atomic_fetch_add(gc, 1, __ATOMIC_ACQ_REL, __HIP_MEMORY_SCOPE_AGENT) & 7) == 7) {
                    if (__hip_atomic_fetch_add(a.bar + 32, 1, __ATOMIC_ACQ_REL, __HIP_MEMORY_SCOPE_AGENT) % 48 == 47) {
                        __hip_atomic_store(a.bar, p + 1, __ATOMIC_RELEASE, __HIP_MEMORY_SCOPE_AGENT);
                    }
                }
                while (__hip_atomic_load(a.bar, __ATOMIC_ACQUIRE, __HIP_MEMORY_SCOPE_AGENT) < p + 1)
                    __builtin_amdgcn_s_sleep(1);
                __threadfence();   // acquire: invalidate L1/L2 so next stage reads fresh h
            }
            __syncthreads();
        }
    }
}

// ---------------- fallback per-phase kernel (only used if cooperative launch fails) ----------------
template<int BF>
__global__ __launch_bounds__(384) void phase_kernel(
    const float* __restrict__ giA, const void* __restrict__ WhhA, const float* __restrict__ bhhA,
    const float* __restrict__ h0r, float* __restrict__ h0w, float* __restrict__ statesA, int hasA,
    const void* __restrict__ WihB, const float* __restrict__ bihB,
    const void* __restrict__ WhhB, const float* __restrict__ bhhB,
    const float* __restrict__ h1r, float* __restrict__ h1w, float* __restrict__ statesB, int hasB) {
    __shared__ float sred[8];
    int bid = blockIdx.x;
    int tid = threadIdx.x;
    int w = tid >> 6, lane = tid & 63;
    auto dotf = [&](const void* Wp, size_t roff, const float* x) -> float {
        float s = 0.f;
        if (BF) {
            const unsigned short* wrow = (const unsigned short*)Wp + roff;
            #pragma unroll
            for (int i = 0; i < 2; ++i) {
                int k = lane * 8 + i * 512;
                us8 wv = *(const us8*)(wrow + k);
                float4 x0 = *(const float4*)(x + k);
                float4 x1 = *(const float4*)(x + k + 4);
                s += bf2f(wv[0]) * x0.x + bf2f(wv[1]) * x0.y + bf2f(wv[2]) * x0.z + bf2f(wv[3]) * x0.w
                   + bf2f(wv[4]) * x1.x + bf2f(wv[5]) * x1.y + bf2f(wv[6]) * x1.z + bf2f(wv[7]) * x1.w;
            }
        } else {
            const float* wrow = (const float*)Wp + roff;
            #pragma unroll
            for (int i = 0; i < 4; ++i) {
                int k = lane * 4 + i * 256;
                float4 wv = *(const float4*)(wrow + k);
                float4 xv = *(const float4*)(x + k);
                s += wv.x * xv.x + wv.y * xv.y + wv.z * xv.z + wv.w * xv.w;
            }
        }
        return s;
    };
    if (bid < 512) {
        if (!hasA) return;
        int tt = w / 3, g = w - tt * 3;
        int jj = bid * 2 + tt;
        float s = dotf(WhhA, (size_t)(g * H + jj) * H, h0r);
        #pragma unroll
        for (int m = 1; m < 64; m <<= 1) s += __shfl_xor(s, m);
        if (lane == 0) sred[w] = s;
        __syncthreads();
        if (tid < 2) {
            int j2 = bid * 2 + tid;
            float s0 = sred[tid * 3], s1 = sred[tid * 3 + 1], s2 = sred[tid * 3 + 2];
            float r = sigmoidf_(giA[j2] + s0 + bhhA[j2]);
            float z = sigmoidf_(giA[H + j2] + s1 + bhhA[H + j2]);
            float n = tanhf(giA[2 * H + j2] + r * (s2 + bhhA[2 * H + j2]));
            float hn = (1.f - z) * n + z * h0r[j2];
            h0w[j2] = hn;
            if (statesA) statesA[j2] = hn;
        }
    } else {
        if (!hasB) return;
        int j = bid - 512;
        int hh = (w >= 3);
        int g = w - hh * 3;
        float s = dotf(hh ? WhhB : WihB, (size_t)(g * H + j) * H, hh ? h1r : h0r);
        #pragma unroll
        for (int m = 1; m < 64; m <<= 1) s += __shfl_xor(s, m);
        if (lane == 0) sred[w] = s;
        __syncthreads();
        if (tid == 0) {
            float r = sigmoidf_(sred[0] + bihB[j] + sred[3] + bhhB[j]);
            float z = sigmoidf_(sred[1] + bihB[H + j] + sred[4] + bhhB[H + j]);
            float n = tanhf(sred[2] + bihB[2 * H + j] + r * (sred[5] + bhhB[2 * H + j]));
            float hn = (1.f - z) * n + z * h1r[j];
            h1w[j] = hn;
            if (statesB) statesB[j] = hn;
        }
    }
}

// ---------------- scores GEMM, split-K ----------------
#define SN 64
#define SK 64
template<int BF>
__global__ __launch_bounds__(256) void scores_kernel(const float* __restrict__ states,
                                                     const void* __restrict__ W,
                                                     const float* __restrict__ bias,
                                                     float* __restrict__ dst, int kc_count) {
    __shared__ float As[SK][64 + 1];
    __shared__ float Bs[SK][SN + 1];
    int n0 = blockIdx.x * SN;
    int kc = blockIdx.y;
    int klen = H / kc_count;
    int kbeg = kc * klen;
    int tid = threadIdx.x;
    int tn = tid & 15, tm = tid >> 4;
    float acc[4][4] = {};
    for (int k0 = kbeg; k0 < kbeg + klen; k0 += SK) {
        for (int i = tid; i < 64 * (SK / 4); i += 256) {
            int m = i >> 4;
            int kq = i & 15;
            float4 v = *(const float4*)(states + (size_t)m * 2048 + H + k0 + kq * 4);
            As[kq * 4 + 0][m] = v.x; As[kq * 4 + 1][m] = v.y;
            As[kq * 4 + 2][m] = v.z; As[kq * 4 + 3][m] = v.w;
        }
        if (BF) {
            for (int i = tid; i < SN * (SK / 8); i += 256) {
                int n = i >> 3;
                int ko = (i & 7) * 8;
                int r = n0 + n;
                if (r < V) {
                    us8 v = *(const us8*)((const unsigned short*)W + (size_t)r * H + k0 + ko);
                    #pragma unroll
                    for (int d = 0; d < 8; ++d) Bs[ko + d][n] = bf2f(v[d]);
                } else {
                    #pragma unroll
                    for (int d = 0; d < 8; ++d) Bs[ko + d][n] = 0.f;
                }
            }
        } else {
            for (int i = tid; i < SN * (SK / 4); i += 256) {
                int n = i >> 4;
                int kq = i & 15;
                int r = n0 + n;
                float4 v = make_float4(0.f, 0.f, 0.f, 0.f);
                if (r < V) v = *(const float4*)((const float*)W + (size_t)r * H + k0 + kq * 4);
                Bs[kq * 4 + 0][n] = v.x; Bs[kq * 4 + 1][n] = v.y;
                Bs[kq * 4 + 2][n] = v.z; Bs[kq * 4 + 3][n] = v.w;
            }
        }
        __syncthreads();
        #pragma unroll 8
        for (int k = 0; k < SK; ++k) {
            float a[4], b[4];
            #pragma unroll
            for (int i = 0; i < 4; ++i) a[i] = As[k][tm * 4 + i];
            #pragma unroll
            for (int j = 0; j < 4; ++j) b[j] = Bs[k][tn * 4 + j];
            #pragma unroll
            for (int i = 0; i < 4; ++i)
                #pragma unroll
                for (int j = 0; j < 4; ++j) acc[i][j] += a[i] * b[j];
        }
        __syncthreads();
    }
    if (kc_count == 1) {
        #pragma unroll
        for (int i = 0; i < 4; ++i) {
            int m = tm * 4 + i;
            #pragma unroll
            for (int j = 0; j < 4; ++j) {
                int r = n0 + tn * 4 + j;
                if (r < V) dst[(size_t)m * V + r] = acc[i][j] + bias[r];
            }
        }
    } else {
        #pragma unroll
        for (int i = 0; i < 4; ++i) {
            int m = tm * 4 + i;
            #pragma unroll
            for (int j = 0; j < 4; ++j) {
                int r = n0 + tn * 4 + j;
                dst[(size_t)(kc * 64 + m) * NPAD + r] = acc[i][j];
            }
        }
    }
}

__global__ __launch_bounds__(256) void reduce_scores_kernel(const float* __restrict__ part,
                                                            const float* __restrict__ bias,
                                                            float* __restrict__ out, int kc_count) {
    int e = blockIdx.x * 256 + threadIdx.x;
    if (e >= 64 * V) return;
    int m = e / V, r = e - m * V;
    float s = bias[r];
    for (int kc = 0; kc < kc_count; ++kc)
        s += part[(size_t)(kc * 64 + m) * NPAD + r];
    out[(size_t)m * V + r] = s;
}

extern "C" void kernel_launch(void* const* d_in, const int* in_sizes, int n_in,
                              void* d_out, int out_size, void* d_ws, size_t ws_size,
                              hipStream_t stream) {
    const int*   char_seq  = (const int*)d_in[0];
    const float* enc_state = (const float*)d_in[1];
    const int*   sos       = (const int*)d_in[2];
    const int*   tgt       = (const int*)d_in[5];
    const float* emb       = (const float*)d_in[6];
    const float* enc_Wih0  = (const float*)d_in[7];
    const float* enc_Whh0  = (const float*)d_in[8];
    const float* enc_bih0  = (const float*)d_in[9];
    const float* enc_bhh0  = (const float*)d_in[10];
    const float* enc_Wih1  = (const float*)d_in[11];
    const float* enc_Whh1  = (const float*)d_in[12];
    const float* enc_bih1  = (const float*)d_in[13];
    const float* enc_bhh1  = (const float*)d_in[14];
    const float* dec_Wih0  = (const float*)d_in[15];
    const float* dec_Whh0  = (const float*)d_in[16];
    const float* dec_bih0  = (const float*)d_in[17];
    const float* dec_bhh0  = (const float*)d_in[18];
    const float* dec_Wih1  = (const float*)d_in[19];
    const float* dec_Whh1  = (const float*)d_in[20];
    const float* dec_bih1  = (const float*)d_in[21];
    const float* dec_bhh1  = (const float*)d_in[22];
    const float* out_W     = (const float*)d_in[23];
    const float* out_b     = (const float*)d_in[24];

    float* ws = (float*)d_ws;
    float* e_enc   = ws;                       // 64*512
    float* e_dec   = e_enc + SEQ * EMB;        // 64*512
    float* gi_enc0 = e_dec + SEQ * EMB;        // 64*3072
    float* gi_dec0 = gi_enc0 + SEQ * H3;       // 64*3072
    float* h0buf   = gi_dec0 + SEQ * H3;       // 2*1024
    float* h1buf   = h0buf + 2 * H;            // 2*1024
    int*   bar     = (int*)(h1buf + 2 * H);    // 128 ints
    float* cur     = h1buf + 2 * H + 128;
    size_t base = (size_t)(cur - ws);
    size_t avail = ws_size / 4 > base ? ws_size / 4 - base : 0;

    const size_t REC_ELEMS = (size_t)H3 * H;
    const size_t REC_SLOTS = REC_ELEMS / 2;
    const size_t OUT_ELEMS = (size_t)V * H;
    const size_t OUT_SLOTS = OUT_ELEMS / 2;

    int bf_rec = (avail >= 6 * REC_SLOTS);
    unsigned short* wbf[6] = {};
    if (bf_rec) {
        for (int m = 0; m < 6; ++m) { wbf[m] = (unsigned short*)cur; cur += REC_SLOTS; }
        avail -= 6 * REC_SLOTS;
    }
    int bf_out = (avail >= OUT_SLOTS);
    unsigned short* owbf = nullptr;
    if (bf_out) { owbf = (unsigned short*)cur; cur += OUT_SLOTS; avail -= OUT_SLOTS; }
    const size_t P4 = (size_t)4 * 64 * NPAD, P2 = (size_t)2 * 64 * NPAD;
    int KC = (avail >= P4) ? 4 : (avail >= P2) ? 2 : 1;
    float* partials = cur;

    float* scores = (float*)d_out;             // 64*10000
    float* states = scores + SEQ * V;          // 64*2048

    if (bf_rec) {
        const float* srcs[6] = { enc_Whh0, enc_Wih1, enc_Whh1, dec_Whh0, dec_Wih1, dec_Whh1 };
        for (int m = 0; m < 6; ++m)
            f2bf_kernel<<<(int)(REC_ELEMS / 2048), 256, 0, stream>>>(srcs[m], wbf[m], (int)REC_ELEMS);
    }
    if (bf_out)
        f2bf_kernel<<<(int)(OUT_ELEMS / 2048), 256, 0, stream>>>(out_W, owbf, (int)OUT_ELEMS);

    init_h_kernel<<<8, 256, 0, stream>>>(enc_state, h0buf, h1buf, bar);
    embed_kernel<<<128, 128, 0, stream>>>(char_seq, sos, tgt, emb, e_enc, e_dec);
    gi0_kernel<<<H3 / 4, 256, 0, stream>>>(e_enc, enc_Wih0, enc_bih0, gi_enc0);
    gi0_kernel<<<H3 / 4, 256, 0, stream>>>(e_dec, dec_Wih0, dec_bih0, gi_dec0);

    bool done = false;
    if (bf_rec) {
        PArgs pa;
        pa.encWhh0 = wbf[0]; pa.encWih1 = wbf[1]; pa.encWhh1 = wbf[2];
        pa.decWhh0 = wbf[3]; pa.decWih1 = wbf[4]; pa.decWhh1 = wbf[5];
        pa.gi_enc0 = gi_enc0; pa.gi_dec0 = gi_dec0;
        pa.enc_bhh0 = enc_bhh0; pa.dec_bhh0 = dec_bhh0;
        pa.enc_bih1 = enc_bih1; pa.enc_bhh1 = enc_bhh1;
        pa.dec_bih1 = dec_bih1; pa.dec_bhh1 = dec_bhh1;
        pa.h0buf = h0buf; pa.h1buf = h1buf; pa.states = states;
        pa.bar = bar;
        void* kparams[] = { (void*)&pa };
        hipError_t err = hipLaunchCooperativeKernel((const void*)persist_kernel,
                                                    dim3(384), dim3(512), kparams, 0, stream);
        done = (err == hipSuccess);
    }

    if (!done) {
        for (int p = 0; p <= 128; ++p) {
            int hasA = (p <= 127);
            int hasB = (p >= 1);
            const float* giA = nullptr; const void* WhhA = nullptr; const float* bhhA = nullptr;
            float* statesA = nullptr;
            if (hasA) {
                if (p < 64) {
                    giA = gi_enc0 + (size_t)p * H3; bhhA = enc_bhh0;
                    WhhA = bf_rec ? (const void*)wbf[0] : (const void*)enc_Whh0;
                } else {
                    int t = p - 64;
                    giA = gi_dec0 + (size_t)t * H3; bhhA = dec_bhh0;
                    WhhA = bf_rec ? (const void*)wbf[3] : (const void*)dec_Whh0;
                    statesA = states + (size_t)t * 2048;
                }
            }
            const void *WihB = nullptr, *WhhB = nullptr;
            const float *bihB = nullptr, *bhhB = nullptr;
            float* statesB = nullptr;
            if (hasB) {
                if (p <= 64) {
                    bihB = enc_bih1; bhhB = enc_bhh1;
                    WihB = bf_rec ? (const void*)wbf[1] : (const void*)enc_Wih1;
                    WhhB = bf_rec ? (const void*)wbf[2] : (const void*)enc_Whh1;
                } else {
                    int t = p - 65;
                    bihB = dec_bih1; bhhB = dec_bhh1;
                    WihB = bf_rec ? (const void*)wbf[4] : (const void*)dec_Wih1;
                    WhhB = bf_rec ? (const void*)wbf[5] : (const void*)dec_Whh1;
                    statesB = states + (size_t)t * 2048 + H;
                }
            }
            float* h0r = h0buf + (p & 1) * H;
            float* h0w = h0buf + ((p + 1) & 1) * H;
            float* h1r = h1buf + (p & 1) * H;
            float* h1w = h1buf + ((p + 1) & 1) * H;
            if (bf_rec)
                phase_kernel<1><<<1536, 384, 0, stream>>>(giA, WhhA, bhhA, h0r, h0w, statesA, hasA,
                                                          WihB, bihB, WhhB, bhhB, h1r, h1w, statesB, hasB);
            else
                phase_kernel<0><<<1536, 384, 0, stream>>>(giA, WhhA, bhhA, h0r, h0w, statesA, hasA,
                                                          WihB, bihB, WhhB, bhhB, h1r, h1w, statesB, hasB);
        }
    }

    const void* Wsc = bf_out ? (const void*)owbf : (const void*)out_W;
    if (KC == 1) {
        if (bf_out)
            scores_kernel<1><<<dim3((V + SN - 1) / SN, 1), 256, 0, stream>>>(states, Wsc, out_b, scores, 1);
        else
            scores_kernel<0><<<dim3((V + SN - 1) / SN, 1), 256, 0, stream>>>(states, Wsc, out_b, scores, 1);
    } else {
        if (bf_out)
            scores_kernel<1><<<dim3((V + SN - 1) / SN, KC), 256, 0, stream>>>(states, Wsc, out_b, partials, KC);
        else
            scores_kernel<0><<<dim3((V + SN - 1) / SN, KC), 256, 0, stream>>>(states, Wsc, out_b, partials, KC);
        reduce_scores_kernel<<<(64 * V + 255) / 256, 256, 0, stream>>>(partials, out_b, scores, KC);
    }
}

// Round 5
// 2847.217 us; speedup vs baseline: 1.9468x; 1.9468x over previous
//
#include <hip/hip_runtime.h>
#include <hip/hip_bf16.h>
#include <math.h>

#define V     10000
#define EMB   512
#define H     1024
#define H3    3072
#define SEQ   64
#define NPAD  10048   // 157*64, padded N for score partials

typedef __attribute__((ext_vector_type(8))) unsigned short us8;
typedef __attribute__((ext_vector_type(8))) unsigned u32x8;

__device__ __forceinline__ float sigmoidf_(float x) { return 1.0f / (1.0f + expf(-x)); }
__device__ __forceinline__ float bf2f(unsigned short u) { return __uint_as_float(((unsigned)u) << 16); }
__device__ __forceinline__ float lof(unsigned u) { return __uint_as_float(u << 16); }
__device__ __forceinline__ float hif(unsigned u) { return __uint_as_float(u & 0xffff0000u); }
__device__ __forceinline__ unsigned short f2bf_rne(float f) {
    unsigned u = __float_as_uint(f);
    unsigned r = u + 0x7FFF + ((u >> 16) & 1);
    return (unsigned short)(r >> 16);
}

// ---------------- f32 -> bf16 weight conversion ----------------
__global__ __launch_bounds__(256) void f2bf_kernel(const float* __restrict__ src,
                                                   unsigned short* __restrict__ dst, int n) {
    int i = (blockIdx.x * 256 + threadIdx.x) * 8;
    if (i >= n) return;
    float4 a = *(const float4*)(src + i);
    float4 b = *(const float4*)(src + i + 4);
    us8 o;
    o[0] = f2bf_rne(a.x); o[1] = f2bf_rne(a.y); o[2] = f2bf_rne(a.z); o[3] = f2bf_rne(a.w);
    o[4] = f2bf_rne(b.x); o[5] = f2bf_rne(b.y); o[6] = f2bf_rne(b.z); o[7] = f2bf_rne(b.w);
    *(us8*)(dst + i) = o;
}

// ---------------- init: h ping-pong buffers + barrier counters ----------------
__global__ void init_h_kernel(const float* __restrict__ enc_state,
                              float* __restrict__ h0buf, float* __restrict__ h1buf,
                              int* __restrict__ bar) {
    int i = blockIdx.x * blockDim.x + threadIdx.x;
    if (i < H)            h0buf[i] = enc_state[i];
    else if (i < 2 * H)   h1buf[H + (i - H)] = enc_state[i];
    if (i < 1024) bar[i] = 0;
}

// ---------------- embedding gather ----------------
__global__ void embed_kernel(const int* __restrict__ cs, const int* __restrict__ sos,
                             const int* __restrict__ tgt, const float* __restrict__ emb,
                             float* __restrict__ e_enc, float* __restrict__ e_dec) {
    int t = blockIdx.x;  // 0..127
    int id;
    float* dst;
    if (t < SEQ) { id = cs[t]; dst = e_enc + (size_t)t * EMB; }
    else         { int td = t - SEQ; id = (td == 0) ? sos[0] : tgt[td - 1]; dst = e_dec + (size_t)td * EMB; }
    const float4* src4 = (const float4*)(emb + (size_t)id * EMB);
    float4* dst4 = (float4*)dst;
    dst4[threadIdx.x] = src4[threadIdx.x];
}

// ---------------- gi0 = e @ Wih0.T + bih0 for all 64 timesteps (f32) ----------------
__global__ __launch_bounds__(256) void gi0_kernel(const float* __restrict__ e,
                                                  const float* __restrict__ W,
                                                  const float* __restrict__ bih,
                                                  float* __restrict__ gi) {
    int wave = (blockIdx.x * 256 + threadIdx.x) >> 6;
    int lane = threadIdx.x & 63;
    if (wave >= H3) return;
    int row = wave;
    float4 w0 = *(const float4*)(W + (size_t)row * EMB + lane * 8);
    float4 w1 = *(const float4*)(W + (size_t)row * EMB + lane * 8 + 4);
    float bb = bih[row];
    for (int t = 0; t < SEQ; ++t) {
        float4 x0 = *(const float4*)(e + (size_t)t * EMB + lane * 8);
        float4 x1 = *(const float4*)(e + (size_t)t * EMB + lane * 8 + 4);
        float s = w0.x * x0.x + w0.y * x0.y + w0.z * x0.z + w0.w * x0.w
                + w1.x * x1.x + w1.y * x1.y + w1.z * x1.z + w1.w * x1.w;
        #pragma unroll
        for (int m = 1; m < 64; m <<= 1) s += __shfl_xor(s, m);
        if (lane == 0) gi[(size_t)t * H3 + row] = s + bb;
    }
}

// ================= persistent recurrence kernel (v2: spill-proof) =================
// 384 blocks x 512 threads. Blocks 0..127 = A (layer0): wave w -> j = bid*8+w, all
// 3 gate rows. Blocks 128..383 = B (layer1): j = (bid-128)*4 + (w>>1); part = w&1
// (0: Wih rows, 1: Whh rows). Weights live in 3 x u32x8 = 24 VGPRs (packed bf16
// pairs; lane l, word q holds elements k=l+128q (lo) and k+64 (hi)). Only the
// CURRENT phase-range's weights are resident; dec set is reloaded once at the
// enc->dec transition (issued during phase tsw-1, overlapping the barrier).
struct PArgs {
    const unsigned short *encWhh0, *encWih1, *encWhh1;
    const unsigned short *decWhh0, *decWih1, *decWhh1;
    const float *gi_enc0, *gi_dec0;
    const float *enc_bhh0, *dec_bhh0;
    const float *enc_bih1, *enc_bhh1, *dec_bih1, *dec_bhh1;
    float *h0buf, *h1buf, *states;
    int *bar;   // [0]=flag, [32]=root counter, [64 + g*16]=48 group counters (1 line each)
};

__device__ __forceinline__ void loadw24(const unsigned short* __restrict__ m,
                                        int j, int lane,
                                        u32x8& w0, u32x8& w1, u32x8& w2) {
    size_t b0 = (size_t)(0 * H + j) * H + lane;
    size_t b1 = (size_t)(1 * H + j) * H + lane;
    size_t b2 = (size_t)(2 * H + j) * H + lane;
    #pragma unroll
    for (int q = 0; q < 8; ++q) {
        w0[q] = (unsigned)m[b0 + 128 * q] | ((unsigned)m[b0 + 128 * q + 64] << 16);
        w1[q] = (unsigned)m[b1 + 128 * q] | ((unsigned)m[b1 + 128 * q + 64] << 16);
        w2[q] = (unsigned)m[b2 + 128 * q] | ((unsigned)m[b2 + 128 * q + 64] << 16);
    }
}

__global__ __launch_bounds__(512, 4) void persist_kernel(PArgs a) {
    __shared__ float xh0[H];
    __shared__ float xh1[H];
    __shared__ float sred[32];
    const int tid = threadIdx.x;
    const int w = tid >> 6, lane = tid & 63;
    const int bid = blockIdx.x;
    const bool isA = (bid < 128);
    int j, part = 0;
    if (isA) j = bid * 8 + w;
    else { int bb = bid - 128; j = bb * 4 + (w >> 1); part = w & 1; }

    const unsigned short* menc = isA ? a.encWhh0 : (part == 0 ? a.encWih1 : a.encWhh1);
    const unsigned short* mdec = isA ? a.decWhh0 : (part == 0 ? a.decWih1 : a.decWhh1);
    const int tsw = isA ? 64 : 65;   // first phase that uses dec weights

    u32x8 w0, w1, w2;
    loadw24(menc, j, lane, w0, w1, w2);

    for (int p = 0; p <= 128; ++p) {
        // stage current h vectors into LDS
        const float* h0r = a.h0buf + (p & 1) * H;
        const float* h1r = a.h1buf + (p & 1) * H;
        if (tid < 256) *(float4*)(xh0 + tid * 4)         = *(const float4*)(h0r + tid * 4);
        else           *(float4*)(xh1 + (tid - 256) * 4) = *(const float4*)(h1r + (tid - 256) * 4);
        __syncthreads();

        const bool hasA = (p <= 127), hasB = (p >= 1);
        const bool active = isA ? hasA : hasB;
        if (active) {
            const float* x = (isA || part == 0) ? xh0 : xh1;
            float s0 = 0.f, s1 = 0.f, s2 = 0.f;
            #pragma unroll
            for (int q = 0; q < 8; ++q) {
                float x0 = x[lane + 128 * q];
                float x1 = x[lane + 128 * q + 64];
                s0 += lof(w0[q]) * x0 + hif(w0[q]) * x1;
                s1 += lof(w1[q]) * x0 + hif(w1[q]) * x1;
                s2 += lof(w2[q]) * x0 + hif(w2[q]) * x1;
            }
            #pragma unroll
            for (int m = 1; m < 64; m <<= 1) {
                s0 += __shfl_xor(s0, m);
                s1 += __shfl_xor(s1, m);
                s2 += __shfl_xor(s2, m);
            }
            if (isA) {
                if (lane == 0) {
                    const float* gi  = (p < 64) ? (a.gi_enc0 + (size_t)p * H3)
                                                : (a.gi_dec0 + (size_t)(p - 64) * H3);
                    const float* bhh = (p < 64) ? a.enc_bhh0 : a.dec_bhh0;
                    float r = sigmoidf_(gi[j] + s0 + bhh[j]);
                    float z = sigmoidf_(gi[H + j] + s1 + bhh[H + j]);
                    float n = tanhf(gi[2 * H + j] + r * (s2 + bhh[2 * H + j]));
                    float hn = (1.f - z) * n + z * xh0[j];
                    a.h0buf[((p + 1) & 1) * H + j] = hn;
                    if (p >= 64) a.states[(size_t)(p - 64) * 2048 + j] = hn;
                }
            } else if (lane == 0) {
                int slot = (w >> 1) * 8 + part * 4;
                sred[slot + 0] = s0; sred[slot + 1] = s1; sred[slot + 2] = s2;
            }
        }
        __syncthreads();
        if (!isA && hasB && tid < 4) {
            int jg = (bid - 128) * 4 + tid;
            const float* bih = (p <= 64) ? a.enc_bih1 : a.dec_bih1;
            const float* bhh = (p <= 64) ? a.enc_bhh1 : a.dec_bhh1;
            float si0 = sred[tid * 8 + 0], si1 = sred[tid * 8 + 1], si2 = sred[tid * 8 + 2];
            float sh0 = sred[tid * 8 + 4], sh1 = sred[tid * 8 + 5], sh2 = sred[tid * 8 + 6];
            float r = sigmoidf_(si0 + bih[jg] + sh0 + bhh[jg]);
            float z = sigmoidf_(si1 + bih[H + jg] + sh1 + bhh[H + jg]);
            float n = tanhf(si2 + bih[2 * H + jg] + r * (sh2 + bhh[2 * H + jg]));
            float hn = (1.f - z) * n + z * xh1[jg];
            a.h1buf[((p + 1) & 1) * H + jg] = hn;
            if (p >= 65) a.states[(size_t)(p - 65) * 2048 + H + jg] = hn;
        }
        // issue the dec weight reload right after the last enc-weight use; the
        // loads fly during the barrier spin below.
        if (p == tsw - 1) loadw24(mdec, j, lane, w0, w1, w2);

        if (p < 128) {
            // ---- grid barrier (hierarchical, monotonic counters) ----
            __syncthreads();
            if (tid == 0) {
                __threadfence();   // release: publish this block's h writes
                int* gc = a.bar + 64 + (bid >> 3) * 16;
                if ((__hip_atomic_fetch_add(gc, 1, __ATOMIC_ACQ_REL, __HIP_MEMORY_SCOPE_AGENT) & 7) == 7) {
                    if (__hip_atomic_fetch_add(a.bar + 32, 1, __ATOMIC_ACQ_REL, __HIP_MEMORY_SCOPE_AGENT) % 48 == 47) {
                        __hip_atomic_store(a.bar, p + 1, __ATOMIC_RELEASE, __HIP_MEMORY_SCOPE_AGENT);
                    }
                }
                while (__hip_atomic_load(a.bar, __ATOMIC_RELAXED, __HIP_MEMORY_SCOPE_AGENT) < p + 1)
                    __builtin_amdgcn_s_sleep(2);
                __threadfence();   // acquire: see other blocks' h writes
            }
            __syncthreads();
        }
    }
}

// ---------------- fallback per-phase kernel (only used if cooperative launch fails) ----------------
template<int BF>
__global__ __launch_bounds__(384) void phase_kernel(
    const float* __restrict__ giA, const void* __restrict__ WhhA, const float* __restrict__ bhhA,
    const float* __restrict__ h0r, float* __restrict__ h0w, float* __restrict__ statesA, int hasA,
    const void* __restrict__ WihB, const float* __restrict__ bihB,
    const void* __restrict__ WhhB, const float* __restrict__ bhhB,
    const float* __restrict__ h1r, float* __restrict__ h1w, float* __restrict__ statesB, int hasB) {
    __shared__ float sred[8];
    int bid = blockIdx.x;
    int tid = threadIdx.x;
    int w = tid >> 6, lane = tid & 63;
    auto dotf = [&](const void* Wp, size_t roff, const float* x) -> float {
        float s = 0.f;
        if (BF) {
            const unsigned short* wrow = (const unsigned short*)Wp + roff;
            #pragma unroll
            for (int i = 0; i < 2; ++i) {
                int k = lane * 8 + i * 512;
                us8 wv = *(const us8*)(wrow + k);
                float4 x0 = *(const float4*)(x + k);
                float4 x1 = *(const float4*)(x + k + 4);
                s += bf2f(wv[0]) * x0.x + bf2f(wv[1]) * x0.y + bf2f(wv[2]) * x0.z + bf2f(wv[3]) * x0.w
                   + bf2f(wv[4]) * x1.x + bf2f(wv[5]) * x1.y + bf2f(wv[6]) * x1.z + bf2f(wv[7]) * x1.w;
            }
        } else {
            const float* wrow = (const float*)Wp + roff;
            #pragma unroll
            for (int i = 0; i < 4; ++i) {
                int k = lane * 4 + i * 256;
                float4 wv = *(const float4*)(wrow + k);
                float4 xv = *(const float4*)(x + k);
                s += wv.x * xv.x + wv.y * xv.y + wv.z * xv.z + wv.w * xv.w;
            }
        }
        return s;
    };
    if (bid < 512) {
        if (!hasA) return;
        int tt = w / 3, g = w - tt * 3;
        int jj = bid * 2 + tt;
        float s = dotf(WhhA, (size_t)(g * H + jj) * H, h0r);
        #pragma unroll
        for (int m = 1; m < 64; m <<= 1) s += __shfl_xor(s, m);
        if (lane == 0) sred[w] = s;
        __syncthreads();
        if (tid < 2) {
            int j2 = bid * 2 + tid;
            float s0 = sred[tid * 3], s1 = sred[tid * 3 + 1], s2 = sred[tid * 3 + 2];
            float r = sigmoidf_(giA[j2] + s0 + bhhA[j2]);
            float z = sigmoidf_(giA[H + j2] + s1 + bhhA[H + j2]);
            float n = tanhf(giA[2 * H + j2] + r * (s2 + bhhA[2 * H + j2]));
            float hn = (1.f - z) * n + z * h0r[j2];
            h0w[j2] = hn;
            if (statesA) statesA[j2] = hn;
        }
    } else {
        if (!hasB) return;
        int j = bid - 512;
        int hh = (w >= 3);
        int g = w - hh * 3;
        float s = dotf(hh ? WhhB : WihB, (size_t)(g * H + j) * H, hh ? h1r : h0r);
        #pragma unroll
        for (int m = 1; m < 64; m <<= 1) s += __shfl_xor(s, m);
        if (lane == 0) sred[w] = s;
        __syncthreads();
        if (tid == 0) {
            float r = sigmoidf_(sred[0] + bihB[j] + sred[3] + bhhB[j]);
            float z = sigmoidf_(sred[1] + bihB[H + j] + sred[4] + bhhB[H + j]);
            float n = tanhf(sred[2] + bihB[2 * H + j] + r * (sred[5] + bhhB[2 * H + j]));
            float hn = (1.f - z) * n + z * h1r[j];
            h1w[j] = hn;
            if (statesB) statesB[j] = hn;
        }
    }
}

// ---------------- scores GEMM, split-K ----------------
#define SN 64
#define SK 64
template<int BF>
__global__ __launch_bounds__(256) void scores_kernel(const float* __restrict__ states,
                                                     const void* __restrict__ W,
                                                     const float* __restrict__ bias,
                                                     float* __restrict__ dst, int kc_count) {
    __shared__ float As[SK][64 + 1];
    __shared__ float Bs[SK][SN + 1];
    int n0 = blockIdx.x * SN;
    int kc = blockIdx.y;
    int klen = H / kc_count;
    int kbeg = kc * klen;
    int tid = threadIdx.x;
    int tn = tid & 15, tm = tid >> 4;
    float acc[4][4] = {};
    for (int k0 = kbeg; k0 < kbeg + klen; k0 += SK) {
        for (int i = tid; i < 64 * (SK / 4); i += 256) {
            int m = i >> 4;
            int kq = i & 15;
            float4 v = *(const float4*)(states + (size_t)m * 2048 + H + k0 + kq * 4);
            As[kq * 4 + 0][m] = v.x; As[kq * 4 + 1][m] = v.y;
            As[kq * 4 + 2][m] = v.z; As[kq * 4 + 3][m] = v.w;
        }
        if (BF) {
            for (int i = tid; i < SN * (SK / 8); i += 256) {
                int n = i >> 3;
                int ko = (i & 7) * 8;
                int r = n0 + n;
                if (r < V) {
                    us8 v = *(const us8*)((const unsigned short*)W + (size_t)r * H + k0 + ko);
                    #pragma unroll
                    for (int d = 0; d < 8; ++d) Bs[ko + d][n] = bf2f(v[d]);
                } else {
                    #pragma unroll
                    for (int d = 0; d < 8; ++d) Bs[ko + d][n] = 0.f;
                }
            }
        } else {
            for (int i = tid; i < SN * (SK / 4); i += 256) {
                int n = i >> 4;
                int kq = i & 15;
                int r = n0 + n;
                float4 v = make_float4(0.f, 0.f, 0.f, 0.f);
                if (r < V) v = *(const float4*)((const float*)W + (size_t)r * H + k0 + kq * 4);
                Bs[kq * 4 + 0][n] = v.x; Bs[kq * 4 + 1][n] = v.y;
                Bs[kq * 4 + 2][n] = v.z; Bs[kq * 4 + 3][n] = v.w;
            }
        }
        __syncthreads();
        #pragma unroll 8
        for (int k = 0; k < SK; ++k) {
            float a[4], b[4];
            #pragma unroll
            for (int i = 0; i < 4; ++i) a[i] = As[k][tm * 4 + i];
            #pragma unroll
            for (int j = 0; j < 4; ++j) b[j] = Bs[k][tn * 4 + j];
            #pragma unroll
            for (int i = 0; i < 4; ++i)
                #pragma unroll
                for (int j = 0; j < 4; ++j) acc[i][j] += a[i] * b[j];
        }
        __syncthreads();
    }
    if (kc_count == 1) {
        #pragma unroll
        for (int i = 0; i < 4; ++i) {
            int m = tm * 4 + i;
            #pragma unroll
            for (int j = 0; j < 4; ++j) {
                int r = n0 + tn * 4 + j;
                if (r < V) dst[(size_t)m * V + r] = acc[i][j] + bias[r];
            }
        }
    } else {
        #pragma unroll
        for (int i = 0; i < 4; ++i) {
            int m = tm * 4 + i;
            #pragma unroll
            for (int j = 0; j < 4; ++j) {
                int r = n0 + tn * 4 + j;
                dst[(size_t)(kc * 64 + m) * NPAD + r] = acc[i][j];
            }
        }
    }
}

__global__ __launch_bounds__(256) void reduce_scores_kernel(const float* __restrict__ part,
                                                            const float* __restrict__ bias,
                                                            float* __restrict__ out, int kc_count) {
    int e = blockIdx.x * 256 + threadIdx.x;
    if (e >= 64 * V) return;
    int m = e / V, r = e - m * V;
    float s = bias[r];
    for (int kc = 0; kc < kc_count; ++kc)
        s += part[(size_t)(kc * 64 + m) * NPAD + r];
    out[(size_t)m * V + r] = s;
}

extern "C" void kernel_launch(void* const* d_in, const int* in_sizes, int n_in,
                              void* d_out, int out_size, void* d_ws, size_t ws_size,
                              hipStream_t stream) {
    const int*   char_seq  = (const int*)d_in[0];
    const float* enc_state = (const float*)d_in[1];
    const int*   sos       = (const int*)d_in[2];
    const int*   tgt       = (const int*)d_in[5];
    const float* emb       = (const float*)d_in[6];
    const float* enc_Wih0  = (const float*)d_in[7];
    const float* enc_Whh0  = (const float*)d_in[8];
    const float* enc_bih0  = (const float*)d_in[9];
    const float* enc_bhh0  = (const float*)d_in[10];
    const float* enc_Wih1  = (const float*)d_in[11];
    const float* enc_Whh1  = (const float*)d_in[12];
    const float* enc_bih1  = (const float*)d_in[13];
    const float* enc_bhh1  = (const float*)d_in[14];
    const float* dec_Wih0  = (const float*)d_in[15];
    const float* dec_Whh0  = (const float*)d_in[16];
    const float* dec_bih0  = (const float*)d_in[17];
    const float* dec_bhh0  = (const float*)d_in[18];
    const float* dec_Wih1  = (const float*)d_in[19];
    const float* dec_Whh1  = (const float*)d_in[20];
    const float* dec_bih1  = (const float*)d_in[21];
    const float* dec_bhh1  = (const float*)d_in[22];
    const float* out_W     = (const float*)d_in[23];
    const float* out_b     = (const float*)d_in[24];

    float* ws = (float*)d_ws;
    float* e_enc   = ws;                       // 64*512
    float* e_dec   = e_enc + SEQ * EMB;        // 64*512
    float* gi_enc0 = e_dec + SEQ * EMB;        // 64*3072
    float* gi_dec0 = gi_enc0 + SEQ * H3;       // 64*3072
    float* h0buf   = gi_dec0 + SEQ * H3;       // 2*1024
    float* h1buf   = h0buf + 2 * H;            // 2*1024
    int*   bar     = (int*)(h1buf + 2 * H);    // 1024 ints (flag/root/48 group lines)
    float* cur     = h1buf + 2 * H + 1024;
    size_t base = (size_t)(cur - ws);
    size_t avail = ws_size / 4 > base ? ws_size / 4 - base : 0;

    const size_t REC_ELEMS = (size_t)H3 * H;
    const size_t REC_SLOTS = REC_ELEMS / 2;
    const size_t OUT_ELEMS = (size_t)V * H;
    const size_t OUT_SLOTS = OUT_ELEMS / 2;

    int bf_rec = (avail >= 6 * REC_SLOTS);
    unsigned short* wbf[6] = {};
    if (bf_rec) {
        for (int m = 0; m < 6; ++m) { wbf[m] = (unsigned short*)cur; cur += REC_SLOTS; }
        avail -= 6 * REC_SLOTS;
    }
    int bf_out = (avail >= OUT_SLOTS);
    unsigned short* owbf = nullptr;
    if (bf_out) { owbf = (unsigned short*)cur; cur += OUT_SLOTS; avail -= OUT_SLOTS; }
    const size_t P4 = (size_t)4 * 64 * NPAD, P2 = (size_t)2 * 64 * NPAD;
    int KC = (avail >= P4) ? 4 : (avail >= P2) ? 2 : 1;
    float* partials = cur;

    float* scores = (float*)d_out;             // 64*10000
    float* states = scores + SEQ * V;          // 64*2048

    if (bf_rec) {
        const float* srcs[6] = { enc_Whh0, enc_Wih1, enc_Whh1, dec_Whh0, dec_Wih1, dec_Whh1 };
        for (int m = 0; m < 6; ++m)
            f2bf_kernel<<<(int)(REC_ELEMS / 2048), 256, 0, stream>>>(srcs[m], wbf[m], (int)REC_ELEMS);
    }
    if (bf_out)
        f2bf_kernel<<<(int)(OUT_ELEMS / 2048), 256, 0, stream>>>(out_W, owbf, (int)OUT_ELEMS);

    init_h_kernel<<<8, 256, 0, stream>>>(enc_state, h0buf, h1buf, bar);
    embed_kernel<<<128, 128, 0, stream>>>(char_seq, sos, tgt, emb, e_enc, e_dec);
    gi0_kernel<<<H3 / 4, 256, 0, stream>>>(e_enc, enc_Wih0, enc_bih0, gi_enc0);
    gi0_kernel<<<H3 / 4, 256, 0, stream>>>(e_dec, dec_Wih0, dec_bih0, gi_dec0);

    bool done = false;
    if (bf_rec) {
        PArgs pa;
        pa.encWhh0 = wbf[0]; pa.encWih1 = wbf[1]; pa.encWhh1 = wbf[2];
        pa.decWhh0 = wbf[3]; pa.decWih1 = wbf[4]; pa.decWhh1 = wbf[5];
        pa.gi_enc0 = gi_enc0; pa.gi_dec0 = gi_dec0;
        pa.enc_bhh0 = enc_bhh0; pa.dec_bhh0 = dec_bhh0;
        pa.enc_bih1 = enc_bih1; pa.enc_bhh1 = enc_bhh1;
        pa.dec_bih1 = dec_bih1; pa.dec_bhh1 = dec_bhh1;
        pa.h0buf = h0buf; pa.h1buf = h1buf; pa.states = states;
        pa.bar = bar;
        void* kparams[] = { (void*)&pa };
        hipError_t err = hipLaunchCooperativeKernel((const void*)persist_kernel,
                                                    dim3(384), dim3(512), kparams, 0, stream);
        done = (err == hipSuccess);
    }

    if (!done) {
        for (int p = 0; p <= 128; ++p) {
            int hasA = (p <= 127);
            int hasB = (p >= 1);
            const float* giA = nullptr; const void* WhhA = nullptr; const float* bhhA = nullptr;
            float* statesA = nullptr;
            if (hasA) {
                if (p < 64) {
                    giA = gi_enc0 + (size_t)p * H3; bhhA = enc_bhh0;
                    WhhA = bf_rec ? (const void*)wbf[0] : (const void*)enc_Whh0;
                } else {
                    int t = p - 64;
                    giA = gi_dec0 + (size_t)t * H3; bhhA = dec_bhh0;
                    WhhA = bf_rec ? (const void*)wbf[3] : (const void*)dec_Whh0;
                    statesA = states + (size_t)t * 2048;
                }
            }
            const void *WihB = nullptr, *WhhB = nullptr;
            const float *bihB = nullptr, *bhhB = nullptr;
            float* statesB = nullptr;
            if (hasB) {
                if (p <= 64) {
                    bihB = enc_bih1; bhhB = enc_bhh1;
                    WihB = bf_rec ? (const void*)wbf[1] : (const void*)enc_Wih1;
                    WhhB = bf_rec ? (const void*)wbf[2] : (const void*)enc_Whh1;
                } else {
                    int t = p - 65;
                    bihB = dec_bih1; bhhB = dec_bhh1;
                    WihB = bf_rec ? (const void*)wbf[4] : (const void*)dec_Wih1;
                    WhhB = bf_rec ? (const void*)wbf[5] : (const void*)dec_Whh1;
                    statesB = states + (size_t)t * 2048 + H;
                }
            }
            float* h0r = h0buf + (p & 1) * H;
            float* h0w = h0buf + ((p + 1) & 1) * H;
            float* h1r = h1buf + (p & 1) * H;
            float* h1w = h1buf + ((p + 1) & 1) * H;
            if (bf_rec)
                phase_kernel<1><<<1536, 384, 0, stream>>>(giA, WhhA, bhhA, h0r, h0w, statesA, hasA,
                                                          WihB, bihB, WhhB, bhhB, h1r, h1w, statesB, hasB);
            else
                phase_kernel<0><<<1536, 384, 0, stream>>>(giA, WhhA, bhhA, h0r, h0w, statesA, hasA,
                                                          WihB, bihB, WhhB, bhhB, h1r, h1w, statesB, hasB);
        }
    }

    const void* Wsc = bf_out ? (const void*)owbf : (const void*)out_W;
    if (KC == 1) {
        if (bf_out)
            scores_kernel<1><<<dim3((V + SN - 1) / SN, 1), 256, 0, stream>>>(states, Wsc, out_b, scores, 1);
        else
            scores_kernel<0><<<dim3((V + SN - 1) / SN, 1), 256, 0, stream>>>(states, Wsc, out_b, scores, 1);
    } else {
        if (bf_out)
            scores_kernel<1><<<dim3((V + SN - 1) / SN, KC), 256, 0, stream>>>(states, Wsc, out_b, partials, KC);
        else
            scores_kernel<0><<<dim3((V + SN - 1) / SN, KC), 256, 0, stream>>>(states, Wsc, out_b, partials, KC);
        reduce_scores_kernel<<<(64 * V + 255) / 256, 256, 0, stream>>>(partials, out_b, scores, KC);
    }
}

// Round 6
// 703.033 us; speedup vs baseline: 7.8845x; 4.0499x over previous
//
#include <hip/hip_runtime.h>
#include <hip/hip_bf16.h>
#include <math.h>

#define V     10000
#define EMB   512
#define H     1024
#define H3    3072
#define SEQ   64
#define NPAD  10048   // 157*64, padded N for score partials

typedef __attribute__((ext_vector_type(8))) unsigned short us8;
typedef __attribute__((ext_vector_type(8))) unsigned u32x8;

__device__ __forceinline__ float sigmoidf_(float x) { return 1.0f / (1.0f + expf(-x)); }
__device__ __forceinline__ float bf2f(unsigned short u) { return __uint_as_float(((unsigned)u) << 16); }
__device__ __forceinline__ float lof(unsigned u) { return __uint_as_float(u << 16); }
__device__ __forceinline__ float hif(unsigned u) { return __uint_as_float(u & 0xffff0000u); }
__device__ __forceinline__ unsigned short f2bf_rne(float f) {
    unsigned u = __float_as_uint(f);
    unsigned r = u + 0x7FFF + ((u >> 16) & 1);
    return (unsigned short)(r >> 16);
}

// ---------------- f32 -> bf16 weight conversion ----------------
__global__ __launch_bounds__(256) void f2bf_kernel(const float* __restrict__ src,
                                                   unsigned short* __restrict__ dst, int n) {
    int i = (blockIdx.x * 256 + threadIdx.x) * 8;
    if (i >= n) return;
    float4 a = *(const float4*)(src + i);
    float4 b = *(const float4*)(src + i + 4);
    us8 o;
    o[0] = f2bf_rne(a.x); o[1] = f2bf_rne(a.y); o[2] = f2bf_rne(a.z); o[3] = f2bf_rne(a.w);
    o[4] = f2bf_rne(b.x); o[5] = f2bf_rne(b.y); o[6] = f2bf_rne(b.z); o[7] = f2bf_rne(b.w);
    *(us8*)(dst + i) = o;
}

// ---------------- init: h ping-pong buffers + barrier counters ----------------
__global__ void init_h_kernel(const float* __restrict__ enc_state,
                              float* __restrict__ h0buf, float* __restrict__ h1buf,
                              int* __restrict__ bar) {
    int i = blockIdx.x * blockDim.x + threadIdx.x;
    if (i < H)            h0buf[i] = enc_state[i];
    else if (i < 2 * H)   h1buf[H + (i - H)] = enc_state[i];
    if (i < 1024) bar[i] = 0;
}

// ---------------- embedding gather ----------------
__global__ void embed_kernel(const int* __restrict__ cs, const int* __restrict__ sos,
                             const int* __restrict__ tgt, const float* __restrict__ emb,
                             float* __restrict__ e_enc, float* __restrict__ e_dec) {
    int t = blockIdx.x;  // 0..127
    int id;
    float* dst;
    if (t < SEQ) { id = cs[t]; dst = e_enc + (size_t)t * EMB; }
    else         { int td = t - SEQ; id = (td == 0) ? sos[0] : tgt[td - 1]; dst = e_dec + (size_t)td * EMB; }
    const float4* src4 = (const float4*)(emb + (size_t)id * EMB);
    float4* dst4 = (float4*)dst;
    dst4[threadIdx.x] = src4[threadIdx.x];
}

// ---------------- gi0 = e @ Wih0.T + bih0 for all 64 timesteps (f32) ----------------
__global__ __launch_bounds__(256) void gi0_kernel(const float* __restrict__ e,
                                                  const float* __restrict__ W,
                                                  const float* __restrict__ bih,
                                                  float* __restrict__ gi) {
    int wave = (blockIdx.x * 256 + threadIdx.x) >> 6;
    int lane = threadIdx.x & 63;
    if (wave >= H3) return;
    int row = wave;
    float4 w0 = *(const float4*)(W + (size_t)row * EMB + lane * 8);
    float4 w1 = *(const float4*)(W + (size_t)row * EMB + lane * 8 + 4);
    float bb = bih[row];
    for (int t = 0; t < SEQ; ++t) {
        float4 x0 = *(const float4*)(e + (size_t)t * EMB + lane * 8);
        float4 x1 = *(const float4*)(e + (size_t)t * EMB + lane * 8 + 4);
        float s = w0.x * x0.x + w0.y * x0.y + w0.z * x0.z + w0.w * x0.w
                + w1.x * x1.x + w1.y * x1.y + w1.z * x1.z + w1.w * x1.w;
        #pragma unroll
        for (int m = 1; m < 64; m <<= 1) s += __shfl_xor(s, m);
        if (lane == 0) gi[(size_t)t * H3 + row] = s + bb;
    }
}

// ================= persistent recurrence kernel (v3: fence-free barrier) =================
// 192 blocks x 1024 threads (16 waves). Blocks 0..63 = A (layer0): wave w -> j = bid*16+w,
// all 3 gate rows in 24 VGPRs. Blocks 64..191 = B (layer1): j = (bid-64)*8 + (w>>1);
// part = w&1 (0: Wih rows, 1: Whh rows). Cross-block h exchange uses AGENT-scope
// (L2-bypassing) atomic loads/stores, so NO threadfence/cache-flush is needed anywhere:
// __syncthreads() drains each wave's vmcnt (stores reach the coherent point) before
// tid0 runs the counter protocol. Read-only data (gi, biases, weights) stays cached.
struct PArgs {
    const unsigned short *encWhh0, *encWih1, *encWhh1;
    const unsigned short *decWhh0, *decWih1, *decWhh1;
    const float *gi_enc0, *gi_dec0;
    const float *enc_bhh0, *dec_bhh0;
    const float *enc_bih1, *enc_bhh1, *dec_bih1, *dec_bhh1;
    float *h0buf, *h1buf, *states;
    int *bar;   // [0]=flag, [32]=root counter, [64 + g*16]=24 group counters (1 line each)
};

__device__ __forceinline__ void loadw24(const unsigned short* __restrict__ m,
                                        int j, int lane,
                                        u32x8& w0, u32x8& w1, u32x8& w2) {
    size_t b0 = (size_t)(0 * H + j) * H + lane;
    size_t b1 = (size_t)(1 * H + j) * H + lane;
    size_t b2 = (size_t)(2 * H + j) * H + lane;
    #pragma unroll
    for (int q = 0; q < 8; ++q) {
        w0[q] = (unsigned)m[b0 + 128 * q] | ((unsigned)m[b0 + 128 * q + 64] << 16);
        w1[q] = (unsigned)m[b1 + 128 * q] | ((unsigned)m[b1 + 128 * q + 64] << 16);
        w2[q] = (unsigned)m[b2 + 128 * q] | ((unsigned)m[b2 + 128 * q + 64] << 16);
    }
}

__global__ __launch_bounds__(1024, 4) void persist_kernel(PArgs a) {
    __shared__ __align__(16) float xh0[H];
    __shared__ __align__(16) float xh1[H];
    __shared__ float sred[64];
    const int tid = threadIdx.x;
    const int w = tid >> 6, lane = tid & 63;
    const int bid = blockIdx.x;
    const bool isA = (bid < 64);
    int j, part = 0;
    if (isA) j = bid * 16 + w;
    else { int bb = bid - 64; j = bb * 8 + (w >> 1); part = w & 1; }

    const unsigned short* menc = isA ? a.encWhh0 : (part == 0 ? a.encWih1 : a.encWhh1);
    const unsigned short* mdec = isA ? a.decWhh0 : (part == 0 ? a.decWih1 : a.decWhh1);
    const int tsw = isA ? 64 : 65;   // first phase that uses dec weights

    u32x8 w0, w1, w2;
    loadw24(menc, j, lane, w0, w1, w2);

    // hoisted biases: A (lane0 of each wave) b0..b2 = bhh rows; B (tid<8) b0..b5 = bih,bhh
    float b0 = 0.f, b1 = 0.f, b2 = 0.f, b3 = 0.f, b4 = 0.f, b5 = 0.f;
    if (isA) {
        if (lane == 0) { b0 = a.enc_bhh0[j]; b1 = a.enc_bhh0[H + j]; b2 = a.enc_bhh0[2 * H + j]; }
    } else if (tid < 8) {
        int jg = (bid - 64) * 8 + tid;
        b0 = a.enc_bih1[jg]; b1 = a.enc_bih1[H + jg]; b2 = a.enc_bih1[2 * H + jg];
        b3 = a.enc_bhh1[jg]; b4 = a.enc_bhh1[H + jg]; b5 = a.enc_bhh1[2 * H + jg];
    }
    // gi prefetch registers (A lane0): gi rows for the current phase
    float g0 = 0.f, g1 = 0.f, g2 = 0.f;
    if (isA && lane == 0) { g0 = a.gi_enc0[j]; g1 = a.gi_enc0[H + j]; g2 = a.gi_enc0[2 * H + j]; }

    for (int p = 0; p <= 128; ++p) {
        // ---- stage current h vectors via agent-scope (bypassing) loads ----
        {
            unsigned long long* h0u = (unsigned long long*)(a.h0buf + (p & 1) * H);
            unsigned long long* h1u = (unsigned long long*)(a.h1buf + (p & 1) * H);
            if (tid < 512) {
                unsigned long long v = __hip_atomic_load(h0u + tid, __ATOMIC_RELAXED, __HIP_MEMORY_SCOPE_AGENT);
                ((unsigned long long*)xh0)[tid] = v;
            } else {
                unsigned long long v = __hip_atomic_load(h1u + (tid - 512), __ATOMIC_RELAXED, __HIP_MEMORY_SCOPE_AGENT);
                ((unsigned long long*)xh1)[tid - 512] = v;
            }
        }
        __syncthreads();

        const bool hasA = (p <= 127), hasB = (p >= 1);
        if (isA ? hasA : hasB) {
            const float* x = (isA || part == 0) ? xh0 : xh1;
            float s0 = 0.f, s1 = 0.f, s2 = 0.f;
            #pragma unroll
            for (int q = 0; q < 8; ++q) {
                float x0 = x[lane + 128 * q];
                float x1 = x[lane + 128 * q + 64];
                s0 += lof(w0[q]) * x0 + hif(w0[q]) * x1;
                s1 += lof(w1[q]) * x0 + hif(w1[q]) * x1;
                s2 += lof(w2[q]) * x0 + hif(w2[q]) * x1;
            }
            #pragma unroll
            for (int m = 1; m < 64; m <<= 1) {
                s0 += __shfl_xor(s0, m);
                s1 += __shfl_xor(s1, m);
                s2 += __shfl_xor(s2, m);
            }
            if (isA) {
                if (lane == 0) {
                    float r = sigmoidf_(g0 + s0 + b0);
                    float z = sigmoidf_(g1 + s1 + b1);
                    float n = tanhf(g2 + r * (s2 + b2));
                    float hn = (1.f - z) * n + z * xh0[j];
                    __hip_atomic_store(&a.h0buf[((p + 1) & 1) * H + j], hn,
                                       __ATOMIC_RELAXED, __HIP_MEMORY_SCOPE_AGENT);
                    if (p >= 64) a.states[(size_t)(p - 64) * 2048 + j] = hn;
                }
            } else if (lane == 0) {
                int slot = (w >> 1) * 8 + part * 4;
                sred[slot + 0] = s0; sred[slot + 1] = s1; sred[slot + 2] = s2;
            }
        }
        __syncthreads();
        if (!isA && hasB && tid < 8) {
            int jg = (bid - 64) * 8 + tid;
            float si0 = sred[tid * 8 + 0], si1 = sred[tid * 8 + 1], si2 = sred[tid * 8 + 2];
            float sh0 = sred[tid * 8 + 4], sh1 = sred[tid * 8 + 5], sh2 = sred[tid * 8 + 6];
            float r = sigmoidf_(si0 + b0 + sh0 + b3);
            float z = sigmoidf_(si1 + b1 + sh1 + b4);
            float n = tanhf(si2 + b2 + r * (sh2 + b5));
            float hn = (1.f - z) * n + z * xh1[jg];
            __hip_atomic_store(&a.h1buf[((p + 1) & 1) * H + jg], hn,
                               __ATOMIC_RELAXED, __HIP_MEMORY_SCOPE_AGENT);
            if (p >= 65) a.states[(size_t)(p - 65) * 2048 + H + jg] = hn;
        }
        // ---- prefetches for the next phase (overlap with barrier) ----
        if (isA && lane == 0 && p < 127) {
            const float* gn = (p + 1 < 64) ? (a.gi_enc0 + (size_t)(p + 1) * H3)
                                           : (a.gi_dec0 + (size_t)(p + 1 - 64) * H3);
            g0 = gn[j]; g1 = gn[H + j]; g2 = gn[2 * H + j];
        }
        if (p == tsw - 1) {
            loadw24(mdec, j, lane, w0, w1, w2);
            if (isA) {
                if (lane == 0) { b0 = a.dec_bhh0[j]; b1 = a.dec_bhh0[H + j]; b2 = a.dec_bhh0[2 * H + j]; }
            } else if (tid < 8) {
                int jg = (bid - 64) * 8 + tid;
                b0 = a.dec_bih1[jg]; b1 = a.dec_bih1[H + jg]; b2 = a.dec_bih1[2 * H + jg];
                b3 = a.dec_bhh1[jg]; b4 = a.dec_bhh1[H + jg]; b5 = a.dec_bhh1[2 * H + jg];
            }
        }

        if (p < 128) {
            // ---- fence-free grid barrier ----
            __syncthreads();   // drains each wave's vmcnt -> all h stores at coherent point
            if (tid == 0) {
                int* gc = a.bar + 64 + (bid >> 3) * 16;   // 24 groups of 8 blocks
                if ((__hip_atomic_fetch_add(gc, 1, __ATOMIC_RELAXED, __HIP_MEMORY_SCOPE_AGENT) & 7) == 7) {
                    if (__hip_atomic_fetch_add(a.bar + 32, 1, __ATOMIC_RELAXED, __HIP_MEMORY_SCOPE_AGENT) % 24 == 23) {
                        __hip_atomic_store(a.bar, p + 1, __ATOMIC_RELAXED, __HIP_MEMORY_SCOPE_AGENT);
                    }
                }
                while (__hip_atomic_load(a.bar, __ATOMIC_RELAXED, __HIP_MEMORY_SCOPE_AGENT) < p + 1)
                    __builtin_amdgcn_s_sleep(1);
            }
            __syncthreads();
        }
    }
}

// ---------------- fallback per-phase kernel (only used if cooperative launch fails) ----------------
template<int BF>
__global__ __launch_bounds__(384) void phase_kernel(
    const float* __restrict__ giA, const void* __restrict__ WhhA, const float* __restrict__ bhhA,
    const float* __restrict__ h0r, float* __restrict__ h0w, float* __restrict__ statesA, int hasA,
    const void* __restrict__ WihB, const float* __restrict__ bihB,
    const void* __restrict__ WhhB, const float* __restrict__ bhhB,
    const float* __restrict__ h1r, float* __restrict__ h1w, float* __restrict__ statesB, int hasB) {
    __shared__ float sred[8];
    int bid = blockIdx.x;
    int tid = threadIdx.x;
    int w = tid >> 6, lane = tid & 63;
    auto dotf = [&](const void* Wp, size_t roff, const float* x) -> float {
        float s = 0.f;
        if (BF) {
            const unsigned short* wrow = (const unsigned short*)Wp + roff;
            #pragma unroll
            for (int i = 0; i < 2; ++i) {
                int k = lane * 8 + i * 512;
                us8 wv = *(const us8*)(wrow + k);
                float4 x0 = *(const float4*)(x + k);
                float4 x1 = *(const float4*)(x + k + 4);
                s += bf2f(wv[0]) * x0.x + bf2f(wv[1]) * x0.y + bf2f(wv[2]) * x0.z + bf2f(wv[3]) * x0.w
                   + bf2f(wv[4]) * x1.x + bf2f(wv[5]) * x1.y + bf2f(wv[6]) * x1.z + bf2f(wv[7]) * x1.w;
            }
        } else {
            const float* wrow = (const float*)Wp + roff;
            #pragma unroll
            for (int i = 0; i < 4; ++i) {
                int k = lane * 4 + i * 256;
                float4 wv = *(const float4*)(wrow + k);
                float4 xv = *(const float4*)(x + k);
                s += wv.x * xv.x + wv.y * xv.y + wv.z * xv.z + wv.w * xv.w;
            }
        }
        return s;
    };
    if (bid < 512) {
        if (!hasA) return;
        int tt = w / 3, g = w - tt * 3;
        int jj = bid * 2 + tt;
        float s = dotf(WhhA, (size_t)(g * H + jj) * H, h0r);
        #pragma unroll
        for (int m = 1; m < 64; m <<= 1) s += __shfl_xor(s, m);
        if (lane == 0) sred[w] = s;
        __syncthreads();
        if (tid < 2) {
            int j2 = bid * 2 + tid;
            float s0 = sred[tid * 3], s1 = sred[tid * 3 + 1], s2 = sred[tid * 3 + 2];
            float r = sigmoidf_(giA[j2] + s0 + bhhA[j2]);
            float z = sigmoidf_(giA[H + j2] + s1 + bhhA[H + j2]);
            float n = tanhf(giA[2 * H + j2] + r * (s2 + bhhA[2 * H + j2]));
            float hn = (1.f - z) * n + z * h0r[j2];
            h0w[j2] = hn;
            if (statesA) statesA[j2] = hn;
        }
    } else {
        if (!hasB) return;
        int j = bid - 512;
        int hh = (w >= 3);
        int g = w - hh * 3;
        float s = dotf(hh ? WhhB : WihB, (size_t)(g * H + j) * H, hh ? h1r : h0r);
        #pragma unroll
        for (int m = 1; m < 64; m <<= 1) s += __shfl_xor(s, m);
        if (lane == 0) sred[w] = s;
        __syncthreads();
        if (tid == 0) {
            float r = sigmoidf_(sred[0] + bihB[j] + sred[3] + bhhB[j]);
            float z = sigmoidf_(sred[1] + bihB[H + j] + sred[4] + bhhB[H + j]);
            float n = tanhf(sred[2] + bihB[2 * H + j] + r * (sred[5] + bhhB[2 * H + j]));
            float hn = (1.f - z) * n + z * h1r[j];
            h1w[j] = hn;
            if (statesB) statesB[j] = hn;
        }
    }
}

// ---------------- scores GEMM, split-K ----------------
#define SN 64
#define SK 64
template<int BF>
__global__ __launch_bounds__(256) void scores_kernel(const float* __restrict__ states,
                                                     const void* __restrict__ W,
                                                     const float* __restrict__ bias,
                                                     float* __restrict__ dst, int kc_count) {
    __shared__ float As[SK][64 + 1];
    __shared__ float Bs[SK][SN + 1];
    int n0 = blockIdx.x * SN;
    int kc = blockIdx.y;
    int klen = H / kc_count;
    int kbeg = kc * klen;
    int tid = threadIdx.x;
    int tn = tid & 15, tm = tid >> 4;
    float acc[4][4] = {};
    for (int k0 = kbeg; k0 < kbeg + klen; k0 += SK) {
        for (int i = tid; i < 64 * (SK / 4); i += 256) {
            int m = i >> 4;
            int kq = i & 15;
            float4 v = *(const float4*)(states + (size_t)m * 2048 + H + k0 + kq * 4);
            As[kq * 4 + 0][m] = v.x; As[kq * 4 + 1][m] = v.y;
            As[kq * 4 + 2][m] = v.z; As[kq * 4 + 3][m] = v.w;
        }
        if (BF) {
            for (int i = tid; i < SN * (SK / 8); i += 256) {
                int n = i >> 3;
                int ko = (i & 7) * 8;
                int r = n0 + n;
                if (r < V) {
                    us8 v = *(const us8*)((const unsigned short*)W + (size_t)r * H + k0 + ko);
                    #pragma unroll
                    for (int d = 0; d < 8; ++d) Bs[ko + d][n] = bf2f(v[d]);
                } else {
                    #pragma unroll
                    for (int d = 0; d < 8; ++d) Bs[ko + d][n] = 0.f;
                }
            }
        } else {
            for (int i = tid; i < SN * (SK / 4); i += 256) {
                int n = i >> 4;
                int kq = i & 15;
                int r = n0 + n;
                float4 v = make_float4(0.f, 0.f, 0.f, 0.f);
                if (r < V) v = *(const float4*)((const float*)W + (size_t)r * H + k0 + kq * 4);
                Bs[kq * 4 + 0][n] = v.x; Bs[kq * 4 + 1][n] = v.y;
                Bs[kq * 4 + 2][n] = v.z; Bs[kq * 4 + 3][n] = v.w;
            }
        }
        __syncthreads();
        #pragma unroll 8
        for (int k = 0; k < SK; ++k) {
            float a[4], b[4];
            #pragma unroll
            for (int i = 0; i < 4; ++i) a[i] = As[k][tm * 4 + i];
            #pragma unroll
            for (int j = 0; j < 4; ++j) b[j] = Bs[k][tn * 4 + j];
            #pragma unroll
            for (int i = 0; i < 4; ++i)
                #pragma unroll
                for (int j = 0; j < 4; ++j) acc[i][j] += a[i] * b[j];
        }
        __syncthreads();
    }
    if (kc_count == 1) {
        #pragma unroll
        for (int i = 0; i < 4; ++i) {
            int m = tm * 4 + i;
            #pragma unroll
            for (int j = 0; j < 4; ++j) {
                int r = n0 + tn * 4 + j;
                if (r < V) dst[(size_t)m * V + r] = acc[i][j] + bias[r];
            }
        }
    } else {
        #pragma unroll
        for (int i = 0; i < 4; ++i) {
            int m = tm * 4 + i;
            #pragma unroll
            for (int j = 0; j < 4; ++j) {
                int r = n0 + tn * 4 + j;
                dst[(size_t)(kc * 64 + m) * NPAD + r] = acc[i][j];
            }
        }
    }
}

__global__ __launch_bounds__(256) void reduce_scores_kernel(const float* __restrict__ part,
                                                            const float* __restrict__ bias,
                                                            float* __restrict__ out, int kc_count) {
    int e = blockIdx.x * 256 + threadIdx.x;
    if (e >= 64 * V) return;
    int m = e / V, r = e - m * V;
    float s = bias[r];
    for (int kc = 0; kc < kc_count; ++kc)
        s += part[(size_t)(kc * 64 + m) * NPAD + r];
    out[(size_t)m * V + r] = s;
}

extern "C" void kernel_launch(void* const* d_in, const int* in_sizes, int n_in,
                              void* d_out, int out_size, void* d_ws, size_t ws_size,
                              hipStream_t stream) {
    const int*   char_seq  = (const int*)d_in[0];
    const float* enc_state = (const float*)d_in[1];
    const int*   sos       = (const int*)d_in[2];
    const int*   tgt       = (const int*)d_in[5];
    const float* emb       = (const float*)d_in[6];
    const float* enc_Wih0  = (const float*)d_in[7];
    const float* enc_Whh0  = (const float*)d_in[8];
    const float* enc_bih0  = (const float*)d_in[9];
    const float* enc_bhh0  = (const float*)d_in[10];
    const float* enc_Wih1  = (const float*)d_in[11];
    const float* enc_Whh1  = (const float*)d_in[12];
    const float* enc_bih1  = (const float*)d_in[13];
    const float* enc_bhh1  = (const float*)d_in[14];
    const float* dec_Wih0  = (const float*)d_in[15];
    const float* dec_Whh0  = (const float*)d_in[16];
    const float* dec_bih0  = (const float*)d_in[17];
    const float* dec_bhh0  = (const float*)d_in[18];
    const float* dec_Wih1  = (const float*)d_in[19];
    const float* dec_Whh1  = (const float*)d_in[20];
    const float* dec_bih1  = (const float*)d_in[21];
    const float* dec_bhh1  = (const float*)d_in[22];
    const float* out_W     = (const float*)d_in[23];
    const float* out_b     = (const float*)d_in[24];

    float* ws = (float*)d_ws;
    float* e_enc   = ws;                       // 64*512
    float* e_dec   = e_enc + SEQ * EMB;        // 64*512
    float* gi_enc0 = e_dec + SEQ * EMB;        // 64*3072
    float* gi_dec0 = gi_enc0 + SEQ * H3;       // 64*3072
    float* h0buf   = gi_dec0 + SEQ * H3;       // 2*1024
    float* h1buf   = h0buf + 2 * H;            // 2*1024
    int*   bar     = (int*)(h1buf + 2 * H);    // 1024 ints (flag/root/24 group lines)
    float* cur     = h1buf + 2 * H + 1024;
    size_t base = (size_t)(cur - ws);
    size_t avail = ws_size / 4 > base ? ws_size / 4 - base : 0;

    const size_t REC_ELEMS = (size_t)H3 * H;
    const size_t REC_SLOTS = REC_ELEMS / 2;
    const size_t OUT_ELEMS = (size_t)V * H;
    const size_t OUT_SLOTS = OUT_ELEMS / 2;

    int bf_rec = (avail >= 6 * REC_SLOTS);
    unsigned short* wbf[6] = {};
    if (bf_rec) {
        for (int m = 0; m < 6; ++m) { wbf[m] = (unsigned short*)cur; cur += REC_SLOTS; }
        avail -= 6 * REC_SLOTS;
    }
    int bf_out = (avail >= OUT_SLOTS);
    unsigned short* owbf = nullptr;
    if (bf_out) { owbf = (unsigned short*)cur; cur += OUT_SLOTS; avail -= OUT_SLOTS; }
    const size_t P4 = (size_t)4 * 64 * NPAD, P2 = (size_t)2 * 64 * NPAD;
    int KC = (avail >= P4) ? 4 : (avail >= P2) ? 2 : 1;
    float* partials = cur;

    float* scores = (float*)d_out;             // 64*10000
    float* states = scores + SEQ * V;          // 64*2048

    if (bf_rec) {
        const float* srcs[6] = { enc_Whh0, enc_Wih1, enc_Whh1, dec_Whh0, dec_Wih1, dec_Whh1 };
        for (int m = 0; m < 6; ++m)
            f2bf_kernel<<<(int)(REC_ELEMS / 2048), 256, 0, stream>>>(srcs[m], wbf[m], (int)REC_ELEMS);
    }
    if (bf_out)
        f2bf_kernel<<<(int)(OUT_ELEMS / 2048), 256, 0, stream>>>(out_W, owbf, (int)OUT_ELEMS);

    init_h_kernel<<<8, 256, 0, stream>>>(enc_state, h0buf, h1buf, bar);
    embed_kernel<<<128, 128, 0, stream>>>(char_seq, sos, tgt, emb, e_enc, e_dec);
    gi0_kernel<<<H3 / 4, 256, 0, stream>>>(e_enc, enc_Wih0, enc_bih0, gi_enc0);
    gi0_kernel<<<H3 / 4, 256, 0, stream>>>(e_dec, dec_Wih0, dec_bih0, gi_dec0);

    bool done = false;
    if (bf_rec) {
        PArgs pa;
        pa.encWhh0 = wbf[0]; pa.encWih1 = wbf[1]; pa.encWhh1 = wbf[2];
        pa.decWhh0 = wbf[3]; pa.decWih1 = wbf[4]; pa.decWhh1 = wbf[5];
        pa.gi_enc0 = gi_enc0; pa.gi_dec0 = gi_dec0;
        pa.enc_bhh0 = enc_bhh0; pa.dec_bhh0 = dec_bhh0;
        pa.enc_bih1 = enc_bih1; pa.enc_bhh1 = enc_bhh1;
        pa.dec_bih1 = dec_bih1; pa.dec_bhh1 = dec_bhh1;
        pa.h0buf = h0buf; pa.h1buf = h1buf; pa.states = states;
        pa.bar = bar;
        void* kparams[] = { (void*)&pa };
        hipError_t err = hipLaunchCooperativeKernel((const void*)persist_kernel,
                                                    dim3(192), dim3(1024), kparams, 0, stream);
        done = (err == hipSuccess);
    }

    if (!done) {
        for (int p = 0; p <= 128; ++p) {
            int hasA = (p <= 127);
            int hasB = (p >= 1);
            const float* giA = nullptr; const void* WhhA = nullptr; const float* bhhA = nullptr;
            float* statesA = nullptr;
            if (hasA) {
                if (p < 64) {
                    giA = gi_enc0 + (size_t)p * H3; bhhA = enc_bhh0;
                    WhhA = bf_rec ? (const void*)wbf[0] : (const void*)enc_Whh0;
                } else {
                    int t = p - 64;
                    giA = gi_dec0 + (size_t)t * H3; bhhA = dec_bhh0;
                    WhhA = bf_rec ? (const void*)wbf[3] : (const void*)dec_Whh0;
                    statesA = states + (size_t)t * 2048;
                }
            }
            const void *WihB = nullptr, *WhhB = nullptr;
            const float *bihB = nullptr, *bhhB = nullptr;
            float* statesB = nullptr;
            if (hasB) {
                if (p <= 64) {
                    bihB = enc_bih1; bhhB = enc_bhh1;
                    WihB = bf_rec ? (const void*)wbf[1] : (const void*)enc_Wih1;
                    WhhB = bf_rec ? (const void*)wbf[2] : (const void*)enc_Whh1;
                } else {
                    int t = p - 65;
                    bihB = dec_bih1; bhhB = dec_bhh1;
                    WihB = bf_rec ? (const void*)wbf[4] : (const void*)dec_Wih1;
                    WhhB = bf_rec ? (const void*)wbf[5] : (const void*)dec_Whh1;
                    statesB = states + (size_t)t * 2048 + H;
                }
            }
            float* h0r = h0buf + (p & 1) * H;
            float* h0w = h0buf + ((p + 1) & 1) * H;
            float* h1r = h1buf + (p & 1) * H;
            float* h1w = h1buf + ((p + 1) & 1) * H;
            if (bf_rec)
                phase_kernel<1><<<1536, 384, 0, stream>>>(giA, WhhA, bhhA, h0r, h0w, statesA, hasA,
                                                          WihB, bihB, WhhB, bhhB, h1r, h1w, statesB, hasB);
            else
                phase_kernel<0><<<1536, 384, 0, stream>>>(giA, WhhA, bhhA, h0r, h0w, statesA, hasA,
                                                          WihB, bihB, WhhB, bhhB, h1r, h1w, statesB, hasB);
        }
    }

    const void* Wsc = bf_out ? (const void*)owbf : (const void*)out_W;
    if (KC == 1) {
        if (bf_out)
            scores_kernel<1><<<dim3((V + SN - 1) / SN, 1), 256, 0, stream>>>(states, Wsc, out_b, scores, 1);
        else
            scores_kernel<0><<<dim3((V + SN - 1) / SN, 1), 256, 0, stream>>>(states, Wsc, out_b, scores, 1);
    } else {
        if (bf_out)
            scores_kernel<1><<<dim3((V + SN - 1) / SN, KC), 256, 0, stream>>>(states, Wsc, out_b, partials, KC);
        else
            scores_kernel<0><<<dim3((V + SN - 1) / SN, KC), 256, 0, stream>>>(states, Wsc, out_b, partials, KC);
        reduce_scores_kernel<<<(64 * V + 255) / 256, 256, 0, stream>>>(partials, out_b, scores, KC);
    }
}